// Round 1
// baseline (630.321 us; speedup 1.0000x reference)
//
#include <hip/hip_runtime.h>

#define N_NODES 100000
#define N_EDGES 3200000
#define CH 256

// ws layout (floats):
//   [0]            max logit (ordered-uint encoding, atomicMax)
//   [1]            total sum of exp (atomicAdd)
//   [2 .. 258)     yu[256]  = sum_n awu[n]*x[n,:]
//   [258 .. 258+N) awu[N]   = unnormalized per-node attention sums
//   [258+N ..)     q[N], k[N]

__device__ __forceinline__ unsigned f2ord(float f) {
    unsigned b = __float_as_uint(f);
    return (b & 0x80000000u) ? ~b : (b | 0x80000000u);
}
__device__ __forceinline__ float ord2f(unsigned u) {
    unsigned b = (u & 0x80000000u) ? (u & 0x7FFFFFFFu) : ~u;
    return __uint_as_float(b);
}

__global__ __launch_bounds__(256) void k_init(float* ws) {
    int i = blockIdx.x * 256 + threadIdx.x;
    if (i == 0) ((unsigned*)ws)[0] = 0x007FFFFFu;  // encodes -inf
    if (i == 1) ws[1] = 0.0f;
    if (i >= 2 && i < 2 + CH + N_NODES) ws[i] = 0.0f;  // yu + awu contiguous
}

// One wave (64 lanes) per node: q[n] = x[n,:].Wq + bq ; k[n] = x[n,:].Wk + bk
__global__ __launch_bounds__(256) void k_qk(const float* __restrict__ x,
                                            const float* __restrict__ Wq,
                                            const float* __restrict__ bq,
                                            const float* __restrict__ Wk,
                                            const float* __restrict__ bk,
                                            float* __restrict__ q,
                                            float* __restrict__ k) {
    int wave = threadIdx.x >> 6;
    int lane = threadIdx.x & 63;
    int n = blockIdx.x * 4 + wave;
    if (n >= N_NODES) return;
    float4 xv = ((const float4*)(x + (size_t)n * CH))[lane];
    float4 wq = ((const float4*)Wq)[lane];
    float4 wk = ((const float4*)Wk)[lane];
    float dq = xv.x * wq.x + xv.y * wq.y + xv.z * wq.z + xv.w * wq.w;
    float dk = xv.x * wk.x + xv.y * wk.y + xv.z * wk.z + xv.w * wk.w;
    #pragma unroll
    for (int off = 32; off; off >>= 1) {
        dq += __shfl_down(dq, off);
        dk += __shfl_down(dk, off);
    }
    if (lane == 0) {
        q[n] = dq + bq[0];
        k[n] = dk + bk[0];
    }
}

// Pass 1 over edges: global max of leaky_relu(q[row]*k[col])
__global__ __launch_bounds__(256) void k_max(const int* __restrict__ ei,
                                             const float* __restrict__ q,
                                             const float* __restrict__ k,
                                             unsigned* __restrict__ maxp) {
    int e = blockIdx.x * 256 + threadIdx.x;
    float s = -3.0e38f;
    if (e < N_EDGES) {
        float v = q[ei[e]] * k[ei[N_EDGES + e]];
        s = (v >= 0.0f) ? v : 0.2f * v;
    }
    #pragma unroll
    for (int off = 32; off; off >>= 1) s = fmaxf(s, __shfl_down(s, off));
    __shared__ float sm[4];
    if ((threadIdx.x & 63) == 0) sm[threadIdx.x >> 6] = s;
    __syncthreads();
    if (threadIdx.x == 0)
        atomicMax(maxp, f2ord(fmaxf(fmaxf(sm[0], sm[1]), fmaxf(sm[2], sm[3]))));
}

// Pass 2 over edges: ex = exp(s - m); scatter to awu[row]; accumulate total
__global__ __launch_bounds__(256) void k_exp(const int* __restrict__ ei,
                                             const float* __restrict__ q,
                                             const float* __restrict__ k,
                                             const unsigned* __restrict__ maxp,
                                             float* __restrict__ awu,
                                             float* __restrict__ totalp) {
    float m = ord2f(*maxp);
    int e = blockIdx.x * 256 + threadIdx.x;
    float ex = 0.0f;
    if (e < N_EDGES) {
        int r = ei[e];
        float v = q[r] * k[ei[N_EDGES + e]];
        v = (v >= 0.0f) ? v : 0.2f * v;
        ex = __expf(v - m);
        atomicAdd(&awu[r], ex);
    }
    #pragma unroll
    for (int off = 32; off; off >>= 1) ex += __shfl_down(ex, off);
    __shared__ float sm[4];
    if ((threadIdx.x & 63) == 0) sm[threadIdx.x >> 6] = ex;
    __syncthreads();
    if (threadIdx.x == 0) atomicAdd(totalp, sm[0] + sm[1] + sm[2] + sm[3]);
}

// yu[c] += sum over this block's nodes of awu[n]*x[n,c]; also write normalized aw out
__global__ __launch_bounds__(256) void k_pool(const float* __restrict__ x,
                                              const float* __restrict__ awu,
                                              const float* __restrict__ totalp,
                                              float* __restrict__ yu,
                                              float* __restrict__ aw_out) {
    int c = threadIdx.x;
    float acc = 0.0f;
    for (int n = blockIdx.x; n < N_NODES; n += gridDim.x) {
        acc += awu[n] * x[(size_t)n * CH + c];
    }
    atomicAdd(&yu[c], acc);
    float inv = 1.0f / (*totalp);
    for (int i = blockIdx.x * 256 + threadIdx.x; i < N_NODES; i += gridDim.x * 256)
        aw_out[i] = awu[i] * inv;
}

// graph_emb[c] = (yu/total) . Wv[:,c] + bv[c]
__global__ __launch_bounds__(256) void k_final(const float* __restrict__ yu,
                                               const float* __restrict__ totalp,
                                               const float* __restrict__ Wv,
                                               const float* __restrict__ bv,
                                               float* __restrict__ out) {
    __shared__ float ys[CH];
    int c = threadIdx.x;
    ys[c] = yu[c] * (1.0f / (*totalp));
    __syncthreads();
    float acc = 0.0f;
    #pragma unroll 8
    for (int kk = 0; kk < CH; ++kk) acc += ys[kk] * Wv[kk * CH + c];
    out[c] = acc + bv[c];
}

extern "C" void kernel_launch(void* const* d_in, const int* in_sizes, int n_in,
                              void* d_out, int out_size, void* d_ws, size_t ws_size,
                              hipStream_t stream) {
    const float* x  = (const float*)d_in[0];
    const int*   ei = (const int*)d_in[1];
    const float* Wq = (const float*)d_in[2];
    const float* bq = (const float*)d_in[3];
    const float* Wk = (const float*)d_in[4];
    const float* bk = (const float*)d_in[5];
    const float* Wv = (const float*)d_in[6];
    const float* bv = (const float*)d_in[7];
    float* out = (float*)d_out;
    float* ws  = (float*)d_ws;

    unsigned* maxp  = (unsigned*)ws;
    float* totalp   = ws + 1;
    float* yu       = ws + 2;
    float* awu      = ws + 258;
    float* q        = ws + 258 + N_NODES;
    float* k        = ws + 258 + 2 * N_NODES;

    hipLaunchKernelGGL(k_init, dim3((2 + CH + N_NODES + 255) / 256), dim3(256), 0, stream, ws);
    hipLaunchKernelGGL(k_qk, dim3((N_NODES + 3) / 4), dim3(256), 0, stream,
                       x, Wq, bq, Wk, bk, q, k);
    hipLaunchKernelGGL(k_max, dim3((N_EDGES + 255) / 256), dim3(256), 0, stream,
                       ei, q, k, maxp);
    hipLaunchKernelGGL(k_exp, dim3((N_EDGES + 255) / 256), dim3(256), 0, stream,
                       ei, q, k, maxp, awu, totalp);
    hipLaunchKernelGGL(k_pool, dim3(512), dim3(256), 0, stream,
                       x, awu, totalp, yu, out + CH);
    hipLaunchKernelGGL(k_final, dim3(1), dim3(256), 0, stream,
                       yu, totalp, Wv, bv, out);
}

// Round 2
// 379.342 us; speedup vs baseline: 1.6616x; 1.6616x over previous
//
#include <hip/hip_runtime.h>

#define N_NODES 100000
#define N_EDGES 3200000
#define CH 256
#define NCOPY 8
#define YCOPY 16
#define GRID_QK 6250    // 16 nodes/block
#define GRID_EXP 12500  // 256 edges/block
#define GRID_POOL 512

// ws layout (floats)
#define OFF_M      0
#define OFF_TOTAL  1
#define OFF_QKMM   16                      // 6250 float4 = 25000
#define OFF_PT     (OFF_QKMM + 25000)      // 12500
#define OFF_YU16   (OFF_PT + 12500)        // 16*256 = 4096   (zeroed)
#define OFF_AWU8   (OFF_YU16 + 4096)       // 8*100000        (zeroed, contiguous w/ YU16)
#define OFF_AWU    (OFF_AWU8 + NCOPY * N_NODES)
#define OFF_Q      (OFF_AWU + N_NODES)
#define OFF_K      (OFF_Q + N_NODES)
#define ZERO_CNT   (4096 + NCOPY * N_NODES)

__global__ __launch_bounds__(256) void k_init(float* ws) {
    int i = blockIdx.x * 256 + threadIdx.x;
    if (i < ZERO_CNT) ws[OFF_YU16 + i] = 0.0f;
}

// 16 nodes/block: q[n]=x[n,:].Wq+bq, k[n]=x[n,:].Wk+bk; per-block min/max partials
__global__ __launch_bounds__(256) void k_qk(const float* __restrict__ x,
                                            const float* __restrict__ Wq,
                                            const float* __restrict__ bq,
                                            const float* __restrict__ Wk,
                                            const float* __restrict__ bk,
                                            float* __restrict__ q,
                                            float* __restrict__ k,
                                            float4* __restrict__ qkmm) {
    int w = threadIdx.x >> 6, lane = threadIdx.x & 63;
    float4 wq = ((const float4*)Wq)[lane];
    float4 wk = ((const float4*)Wk)[lane];
    float bqs = bq[0], bks = bk[0];
    float qmax = -3.0e38f, qmin = 3.0e38f, kmax = -3.0e38f, kmin = 3.0e38f;
    int base = blockIdx.x * 16 + w * 4;
    #pragma unroll
    for (int i = 0; i < 4; ++i) {
        int n = base + i;
        float4 xv = ((const float4*)(x + (size_t)n * CH))[lane];
        float dq = fmaf(xv.x, wq.x, fmaf(xv.y, wq.y, fmaf(xv.z, wq.z, xv.w * wq.w)));
        float dk = fmaf(xv.x, wk.x, fmaf(xv.y, wk.y, fmaf(xv.z, wk.z, xv.w * wk.w)));
        #pragma unroll
        for (int off = 32; off; off >>= 1) {
            dq += __shfl_down(dq, off);
            dk += __shfl_down(dk, off);
        }
        if (lane == 0) {
            float qq = dq + bqs, kk = dk + bks;
            q[n] = qq; k[n] = kk;
            qmax = fmaxf(qmax, qq); qmin = fminf(qmin, qq);
            kmax = fmaxf(kmax, kk); kmin = fminf(kmin, kk);
        }
    }
    __shared__ float4 sm[4];
    if (lane == 0) sm[w] = make_float4(qmax, qmin, kmax, kmin);
    __syncthreads();
    if (threadIdx.x == 0) {
        float4 r = sm[0];
        #pragma unroll
        for (int j = 1; j < 4; ++j) {
            r.x = fmaxf(r.x, sm[j].x); r.y = fminf(r.y, sm[j].y);
            r.z = fmaxf(r.z, sm[j].z); r.w = fminf(r.w, sm[j].w);
        }
        qkmm[blockIdx.x] = r;
    }
}

// reduce qkmm -> m = lrelu(max corner product) >= max logit over all edges
__global__ __launch_bounds__(256) void k_bound(const float4* __restrict__ qkmm,
                                               float* __restrict__ mp) {
    float qmax = -3.0e38f, qmin = 3.0e38f, kmax = -3.0e38f, kmin = 3.0e38f;
    for (int i = threadIdx.x; i < GRID_QK; i += 256) {
        float4 r = qkmm[i];
        qmax = fmaxf(qmax, r.x); qmin = fminf(qmin, r.y);
        kmax = fmaxf(kmax, r.z); kmin = fminf(kmin, r.w);
    }
    #pragma unroll
    for (int off = 32; off; off >>= 1) {
        qmax = fmaxf(qmax, __shfl_down(qmax, off));
        qmin = fminf(qmin, __shfl_down(qmin, off));
        kmax = fmaxf(kmax, __shfl_down(kmax, off));
        kmin = fminf(kmin, __shfl_down(kmin, off));
    }
    __shared__ float4 sm[4];
    if ((threadIdx.x & 63) == 0) sm[threadIdx.x >> 6] = make_float4(qmax, qmin, kmax, kmin);
    __syncthreads();
    if (threadIdx.x == 0) {
        float4 r = sm[0];
        #pragma unroll
        for (int j = 1; j < 4; ++j) {
            r.x = fmaxf(r.x, sm[j].x); r.y = fminf(r.y, sm[j].y);
            r.z = fmaxf(r.z, sm[j].z); r.w = fminf(r.w, sm[j].w);
        }
        float p = fmaxf(fmaxf(r.x * r.z, r.x * r.w), fmaxf(r.y * r.z, r.y * r.w));
        mp[0] = (p >= 0.0f) ? p : 0.2f * p;
    }
}

// one edge/thread: ex = exp(lrelu(q[r]*k[c]) - m); privatized scatter + per-block total
__global__ __launch_bounds__(256) void k_exp(const int* __restrict__ ei,
                                             const float* __restrict__ q,
                                             const float* __restrict__ k,
                                             const float* __restrict__ mp,
                                             float* __restrict__ awu8,
                                             float* __restrict__ pt) {
    float m = mp[0];
    int e = blockIdx.x * 256 + threadIdx.x;  // grid covers exactly N_EDGES
    int r = ei[e];
    int c = ei[N_EDGES + e];
    float v = q[r] * k[c];
    v = (v >= 0.0f) ? v : 0.2f * v;
    float ex = __expf(v - m);
    atomicAdd(&awu8[(size_t)(blockIdx.x & (NCOPY - 1)) * N_NODES + r], ex);
    float s = ex;
    #pragma unroll
    for (int off = 32; off; off >>= 1) s += __shfl_down(s, off);
    __shared__ float sm[4];
    if ((threadIdx.x & 63) == 0) sm[threadIdx.x >> 6] = s;
    __syncthreads();
    if (threadIdx.x == 0) pt[blockIdx.x] = sm[0] + sm[1] + sm[2] + sm[3];
}

__global__ __launch_bounds__(256) void k_total(const float* __restrict__ pt,
                                               float* __restrict__ totalp) {
    float s = 0.0f;
    for (int i = threadIdx.x; i < GRID_EXP; i += 256) s += pt[i];
    #pragma unroll
    for (int off = 32; off; off >>= 1) s += __shfl_down(s, off);
    __shared__ float sm[4];
    if ((threadIdx.x & 63) == 0) sm[threadIdx.x >> 6] = s;
    __syncthreads();
    if (threadIdx.x == 0) totalp[0] = sm[0] + sm[1] + sm[2] + sm[3];
}

__global__ __launch_bounds__(256) void k_fold(const float* __restrict__ awu8,
                                              float* __restrict__ awu) {
    int n = blockIdx.x * 256 + threadIdx.x;
    if (n < N_NODES) {
        float s = 0.0f;
        #pragma unroll
        for (int j = 0; j < NCOPY; ++j) s += awu8[(size_t)j * N_NODES + n];
        awu[n] = s;
    }
}

// yu16[copy][c] += sum_n awu[n]*x[n,c]; aw_out = awu/total
__global__ __launch_bounds__(256) void k_pool(const float* __restrict__ x,
                                              const float* __restrict__ awu,
                                              const float* __restrict__ totalp,
                                              float* __restrict__ yu16,
                                              float* __restrict__ aw_out) {
    int t = threadIdx.x, s = t >> 6, g = t & 63;
    const float4* X4 = (const float4*)x;
    float4 acc = make_float4(0.f, 0.f, 0.f, 0.f);
    for (int base = blockIdx.x * 8; base < N_NODES; base += GRID_POOL * 8) {
        float a0 = awu[base + s];
        float a1 = awu[base + 4 + s];
        float4 x0 = X4[(size_t)(base + s) * 64 + g];
        float4 x1 = X4[(size_t)(base + 4 + s) * 64 + g];
        acc.x = fmaf(a0, x0.x, acc.x); acc.y = fmaf(a0, x0.y, acc.y);
        acc.z = fmaf(a0, x0.z, acc.z); acc.w = fmaf(a0, x0.w, acc.w);
        acc.x = fmaf(a1, x1.x, acc.x); acc.y = fmaf(a1, x1.y, acc.y);
        acc.z = fmaf(a1, x1.z, acc.z); acc.w = fmaf(a1, x1.w, acc.w);
    }
    __shared__ float4 tmp4[4][64];
    tmp4[s][g] = acc;
    __syncthreads();
    const float* tmp = (const float*)tmp4;
    int c = t;
    float sum = tmp[0 * 256 + c] + tmp[1 * 256 + c] + tmp[2 * 256 + c] + tmp[3 * 256 + c];
    atomicAdd(&yu16[(blockIdx.x & (YCOPY - 1)) * 256 + c], sum);
    float inv = 1.0f / totalp[0];
    for (int i = blockIdx.x * 256 + t; i < N_NODES; i += GRID_POOL * 256)
        aw_out[i] = awu[i] * inv;
}

// block b computes out[b] = (yu/total) . Wv[:,b] + bv[b]
__global__ __launch_bounds__(256) void k_final(const float* __restrict__ yu16,
                                               const float* __restrict__ totalp,
                                               const float* __restrict__ Wv,
                                               const float* __restrict__ bv,
                                               float* __restrict__ out) {
    int t = threadIdx.x, b = blockIdx.x;
    float inv = 1.0f / totalp[0];
    float y = 0.0f;
    #pragma unroll
    for (int j = 0; j < YCOPY; ++j) y += yu16[j * 256 + t];
    y *= inv;
    float val = y * Wv[(size_t)t * CH + b];
    #pragma unroll
    for (int off = 32; off; off >>= 1) val += __shfl_down(val, off);
    __shared__ float sm[4];
    if ((t & 63) == 0) sm[t >> 6] = val;
    __syncthreads();
    if (t == 0) out[b] = sm[0] + sm[1] + sm[2] + sm[3] + bv[b];
}

extern "C" void kernel_launch(void* const* d_in, const int* in_sizes, int n_in,
                              void* d_out, int out_size, void* d_ws, size_t ws_size,
                              hipStream_t stream) {
    const float* x  = (const float*)d_in[0];
    const int*   ei = (const int*)d_in[1];
    const float* Wq = (const float*)d_in[2];
    const float* bq = (const float*)d_in[3];
    const float* Wk = (const float*)d_in[4];
    const float* bk = (const float*)d_in[5];
    const float* Wv = (const float*)d_in[6];
    const float* bv = (const float*)d_in[7];
    float* out = (float*)d_out;
    float* ws  = (float*)d_ws;

    float*  mp     = ws + OFF_M;
    float*  totalp = ws + OFF_TOTAL;
    float4* qkmm   = (float4*)(ws + OFF_QKMM);
    float*  pt     = ws + OFF_PT;
    float*  yu16   = ws + OFF_YU16;
    float*  awu8   = ws + OFF_AWU8;
    float*  awu    = ws + OFF_AWU;
    float*  q      = ws + OFF_Q;
    float*  k      = ws + OFF_K;

    hipLaunchKernelGGL(k_init, dim3((ZERO_CNT + 255) / 256), dim3(256), 0, stream, ws);
    hipLaunchKernelGGL(k_qk, dim3(GRID_QK), dim3(256), 0, stream,
                       x, Wq, bq, Wk, bk, q, k, qkmm);
    hipLaunchKernelGGL(k_bound, dim3(1), dim3(256), 0, stream, qkmm, mp);
    hipLaunchKernelGGL(k_exp, dim3(GRID_EXP), dim3(256), 0, stream,
                       ei, q, k, mp, awu8, pt);
    hipLaunchKernelGGL(k_total, dim3(1), dim3(256), 0, stream, pt, totalp);
    hipLaunchKernelGGL(k_fold, dim3((N_NODES + 255) / 256), dim3(256), 0, stream,
                       awu8, awu);
    hipLaunchKernelGGL(k_pool, dim3(GRID_POOL), dim3(256), 0, stream,
                       x, awu, totalp, yu16, out + CH);
    hipLaunchKernelGGL(k_final, dim3(CH), dim3(256), 0, stream,
                       yu16, totalp, Wv, bv, out);
}

// Round 3
// 338.076 us; speedup vs baseline: 1.8644x; 1.1221x over previous
//
#include <hip/hip_runtime.h>

#define N_NODES 100000
#define N_EDGES 3200000
#define CH 256

#define NB 391          // buckets of 256 nodes: bucket = row >> 8
#define GA 768          // A-phase blocks (= 256*3 for the scan kernel)
#define EPB 4167        // edges per A-block (768*4167 >= 3.2M)
#define GRID_QK 1563    // 64 nodes/block
#define GRID_POOL 512
#define YCOPY 16
#define NCOPY 8         // fallback privatization

// ---------------- full-path ws layout (floats) ----------------
#define F_M        0
#define F_TOTAL    1
#define F_QKMM     16                  // 1563 float4 = 6252
#define F_PTOT     6272                // 391
#define F_BSTART   6672                // 392 ints
#define F_BTOT     7072                // 391 ints
#define F_YU16     7472                // 4096 (zeroed)
#define F_AWU      11584               // 100000
#define F_Q        111584
#define F_K        211584
#define F_HIST     311584              // 768*391 = 300288 ints
#define F_PAIRS    611872              // 3.2M int2 = 6400000 floats
#define FULL_FLOATS 7011872            // ~28.05 MB

// ---------------- fallback ws layout (floats) ----------------
#define B_M        0
#define B_TOTAL    1
#define B_QKMM     16
#define B_PTOT     6272
#define B_YU16     6672                // zero range starts here
#define B_AWU8     10784
#define B_AWU      810784
#define B_Q        910784
#define B_K        1010784
#define FB_ZERO_CNT (B_AWU8 + NCOPY * N_NODES - B_YU16)

__global__ __launch_bounds__(256) void k_init(float* p, int cnt) {
    int i = blockIdx.x * 256 + threadIdx.x;
    if (i < cnt) p[i] = 0.0f;
}

// 64 nodes/block: q[n]=x.Wq+bq, k[n]=x.Wk+bk; per-block qk min/max partial
__global__ __launch_bounds__(256) void k_qk(const float* __restrict__ x,
                                            const float* __restrict__ Wq,
                                            const float* __restrict__ bq,
                                            const float* __restrict__ Wk,
                                            const float* __restrict__ bk,
                                            float* __restrict__ q,
                                            float* __restrict__ k,
                                            float4* __restrict__ qkmm) {
    int w = threadIdx.x >> 6, lane = threadIdx.x & 63;
    float4 wq = ((const float4*)Wq)[lane];
    float4 wk = ((const float4*)Wk)[lane];
    float bqs = bq[0], bks = bk[0];
    float qmax = -3.0e38f, qmin = 3.0e38f, kmax = -3.0e38f, kmin = 3.0e38f;
    int base = blockIdx.x * 64 + w * 16;
    #pragma unroll 4
    for (int i = 0; i < 16; ++i) {
        int n = base + i;
        if (n < N_NODES) {
            float4 xv = ((const float4*)(x + (size_t)n * CH))[lane];
            float dq = fmaf(xv.x, wq.x, fmaf(xv.y, wq.y, fmaf(xv.z, wq.z, xv.w * wq.w)));
            float dk = fmaf(xv.x, wk.x, fmaf(xv.y, wk.y, fmaf(xv.z, wk.z, xv.w * wk.w)));
            #pragma unroll
            for (int off = 32; off; off >>= 1) {
                dq += __shfl_down(dq, off);
                dk += __shfl_down(dk, off);
            }
            if (lane == 0) {
                float qq = dq + bqs, kk = dk + bks;
                q[n] = qq; k[n] = kk;
                qmax = fmaxf(qmax, qq); qmin = fminf(qmin, qq);
                kmax = fmaxf(kmax, kk); kmin = fminf(kmin, kk);
            }
        }
    }
    __shared__ float4 sm[4];
    if (lane == 0) sm[w] = make_float4(qmax, qmin, kmax, kmin);
    __syncthreads();
    if (threadIdx.x == 0) {
        float4 r = sm[0];
        #pragma unroll
        for (int j = 1; j < 4; ++j) {
            r.x = fmaxf(r.x, sm[j].x); r.y = fminf(r.y, sm[j].y);
            r.z = fmaxf(r.z, sm[j].z); r.w = fminf(r.w, sm[j].w);
        }
        qkmm[blockIdx.x] = r;
    }
}

// ---------- full path: counting-sort scatter ----------

// A1: per-block bucket histogram (LDS atomics only)
__global__ __launch_bounds__(256) void k_hist(const int* __restrict__ ei,
                                              int* __restrict__ hist) {
    __shared__ int cnt[NB];
    int t = threadIdx.x, blk = blockIdx.x;
    for (int i = t; i < NB; i += 256) cnt[i] = 0;
    __syncthreads();
    int e0 = blk * EPB, e1 = min(e0 + EPB, N_EDGES);
    for (int e = e0 + t; e < e1; e += 256) atomicAdd(&cnt[ei[e] >> 8], 1);
    __syncthreads();
    for (int i = t; i < NB; i += 256) hist[(size_t)blk * NB + i] = cnt[i];
}

// A2: per-bucket exclusive scan across the 768 blocks (in-place hist->offs), bucket totals
__global__ __launch_bounds__(256) void k_scan(int* __restrict__ hist,
                                              int* __restrict__ btot) {
    int b = blockIdx.x, t = threadIdx.x;
    int v[3]; int s = 0;
    #pragma unroll
    for (int j = 0; j < 3; ++j) { v[j] = hist[(size_t)(t * 3 + j) * NB + b]; s += v[j]; }
    __shared__ int sc[256];
    sc[t] = s;
    __syncthreads();
    #pragma unroll
    for (int d = 1; d < 256; d <<= 1) {
        int add = (t >= d) ? sc[t - d] : 0;
        __syncthreads();
        sc[t] += add;
        __syncthreads();
    }
    int run = sc[t] - s;  // exclusive prefix
    #pragma unroll
    for (int j = 0; j < 3; ++j) { hist[(size_t)(t * 3 + j) * NB + b] = run; run += v[j]; }
    if (t == 255) btot[b] = run;
}

// A2b: bucket base offsets (serial over 391) + softmax shift m from qk corner bound
__global__ __launch_bounds__(256) void k_bstart(const int* __restrict__ btot,
                                                int* __restrict__ bstart,
                                                const float4* __restrict__ qkmm,
                                                float* __restrict__ mp) {
    __shared__ int sh[NB];
    int t = threadIdx.x;
    for (int i = t; i < NB; i += 256) sh[i] = btot[i];
    float qmax = -3.0e38f, qmin = 3.0e38f, kmax = -3.0e38f, kmin = 3.0e38f;
    for (int i = t; i < GRID_QK; i += 256) {
        float4 r = qkmm[i];
        qmax = fmaxf(qmax, r.x); qmin = fminf(qmin, r.y);
        kmax = fmaxf(kmax, r.z); kmin = fminf(kmin, r.w);
    }
    #pragma unroll
    for (int off = 32; off; off >>= 1) {
        qmax = fmaxf(qmax, __shfl_down(qmax, off));
        qmin = fminf(qmin, __shfl_down(qmin, off));
        kmax = fmaxf(kmax, __shfl_down(kmax, off));
        kmin = fminf(kmin, __shfl_down(kmin, off));
    }
    __shared__ float4 smf[4];
    if ((t & 63) == 0) smf[t >> 6] = make_float4(qmax, qmin, kmax, kmin);
    __syncthreads();
    if (t == 0) {
        float4 r = smf[0];
        #pragma unroll
        for (int j = 1; j < 4; ++j) {
            r.x = fmaxf(r.x, smf[j].x); r.y = fminf(r.y, smf[j].y);
            r.z = fmaxf(r.z, smf[j].z); r.w = fminf(r.w, smf[j].w);
        }
        float p = fmaxf(fmaxf(r.x * r.z, r.x * r.w), fmaxf(r.y * r.z, r.y * r.w));
        mp[0] = (p >= 0.0f) ? p : 0.2f * p;
        int run = 0;
        for (int i = 0; i < NB; ++i) { bstart[i] = run; run += sh[i]; }
        bstart[NB] = run;
    }
}

// A3: compute exp and scatter (row, exp) pairs to exact sorted positions
__global__ __launch_bounds__(256) void k_scatter(const int* __restrict__ ei,
                                                 const float* __restrict__ q,
                                                 const float* __restrict__ k,
                                                 const float* __restrict__ mp,
                                                 const int* __restrict__ offs,
                                                 const int* __restrict__ bstart,
                                                 int2* __restrict__ pairs) {
    __shared__ int cnt[NB];
    __shared__ int bst[NB];
    int t = threadIdx.x, blk = blockIdx.x;
    for (int i = t; i < NB; i += 256) {
        cnt[i] = offs[(size_t)blk * NB + i];
        bst[i] = bstart[i];
    }
    float m = mp[0];
    __syncthreads();
    int e0 = blk * EPB, e1 = min(e0 + EPB, N_EDGES);
    for (int e = e0 + t; e < e1; e += 256) {
        int r = ei[e], c = ei[N_EDGES + e];
        float v = q[r] * k[c];
        v = (v >= 0.0f) ? v : 0.2f * v;
        float ex = __expf(v - m);
        int b = r >> 8;
        int rank = atomicAdd(&cnt[b], 1);
        pairs[bst[b] + rank] = make_int2(r, __float_as_int(ex));
    }
}

// B: per-bucket dense aggregation in LDS -> awu + per-block total partial
__global__ __launch_bounds__(256) void k_agg(const int2* __restrict__ pairs,
                                             const int* __restrict__ bstart,
                                             float* __restrict__ awu,
                                             float* __restrict__ ptot) {
    __shared__ float acc[256];
    int t = threadIdx.x, b = blockIdx.x;
    acc[t] = 0.0f;
    __syncthreads();
    int s0 = bstart[b], s1 = bstart[b + 1];
    for (int i = s0 + t; i < s1; i += 256) {
        int2 p = pairs[i];
        atomicAdd(&acc[p.x & 255], __int_as_float(p.y));
    }
    __syncthreads();
    float a = acc[t];
    int n = b * 256 + t;
    if (n < N_NODES) awu[n] = a;
    float s = a;
    #pragma unroll
    for (int off = 32; off; off >>= 1) s += __shfl_down(s, off);
    __shared__ float sm[4];
    if ((t & 63) == 0) sm[t >> 6] = s;
    __syncthreads();
    if (t == 0) ptot[b] = sm[0] + sm[1] + sm[2] + sm[3];
}

// sum of partials -> total
__global__ __launch_bounds__(256) void k_total2(const float* __restrict__ ptot,
                                                int n, float* __restrict__ totalp) {
    int t = threadIdx.x;
    float s = 0.0f;
    for (int i = t; i < n; i += 256) s += ptot[i];
    #pragma unroll
    for (int off = 32; off; off >>= 1) s += __shfl_down(s, off);
    __shared__ float sm[4];
    if ((t & 63) == 0) sm[t >> 6] = s;
    __syncthreads();
    if (t == 0) totalp[0] = sm[0] + sm[1] + sm[2] + sm[3];
}

// ---------- fallback path (small ws): R2-style privatized atomics ----------
__global__ __launch_bounds__(256) void fb_exp(const int* __restrict__ ei,
                                              const float* __restrict__ q,
                                              const float* __restrict__ k,
                                              const float* __restrict__ mp,
                                              float* __restrict__ awu8) {
    float m = mp[0];
    int e = blockIdx.x * 256 + threadIdx.x;
    if (e < N_EDGES) {
        int r = ei[e];
        float v = q[r] * k[ei[N_EDGES + e]];
        v = (v >= 0.0f) ? v : 0.2f * v;
        atomicAdd(&awu8[(size_t)(blockIdx.x & (NCOPY - 1)) * N_NODES + r], __expf(v - m));
    }
}

__global__ __launch_bounds__(256) void fb_fold(const float* __restrict__ awu8,
                                               float* __restrict__ awu,
                                               float* __restrict__ ptot) {
    int t = threadIdx.x;
    int n = blockIdx.x * 256 + t;
    float s = 0.0f;
    if (n < N_NODES) {
        #pragma unroll
        for (int j = 0; j < NCOPY; ++j) s += awu8[(size_t)j * N_NODES + n];
        awu[n] = s;
    }
    #pragma unroll
    for (int off = 32; off; off >>= 1) s += __shfl_down(s, off);
    __shared__ float sm[4];
    if ((t & 63) == 0) sm[t >> 6] = s;
    __syncthreads();
    if (t == 0) ptot[blockIdx.x] = sm[0] + sm[1] + sm[2] + sm[3];
}

__global__ __launch_bounds__(256) void fb_bound(const float4* __restrict__ qkmm,
                                                float* __restrict__ mp) {
    int t = threadIdx.x;
    float qmax = -3.0e38f, qmin = 3.0e38f, kmax = -3.0e38f, kmin = 3.0e38f;
    for (int i = t; i < GRID_QK; i += 256) {
        float4 r = qkmm[i];
        qmax = fmaxf(qmax, r.x); qmin = fminf(qmin, r.y);
        kmax = fmaxf(kmax, r.z); kmin = fminf(kmin, r.w);
    }
    #pragma unroll
    for (int off = 32; off; off >>= 1) {
        qmax = fmaxf(qmax, __shfl_down(qmax, off));
        qmin = fminf(qmin, __shfl_down(qmin, off));
        kmax = fmaxf(kmax, __shfl_down(kmax, off));
        kmin = fminf(kmin, __shfl_down(kmin, off));
    }
    __shared__ float4 smf[4];
    if ((t & 63) == 0) smf[t >> 6] = make_float4(qmax, qmin, kmax, kmin);
    __syncthreads();
    if (t == 0) {
        float4 r = smf[0];
        #pragma unroll
        for (int j = 1; j < 4; ++j) {
            r.x = fmaxf(r.x, smf[j].x); r.y = fminf(r.y, smf[j].y);
            r.z = fmaxf(r.z, smf[j].z); r.w = fminf(r.w, smf[j].w);
        }
        float p = fmaxf(fmaxf(r.x * r.z, r.x * r.w), fmaxf(r.y * r.z, r.y * r.w));
        mp[0] = (p >= 0.0f) ? p : 0.2f * p;
    }
}

// ---------- shared tail ----------
__global__ __launch_bounds__(256) void k_pool(const float* __restrict__ x,
                                              const float* __restrict__ awu,
                                              const float* __restrict__ totalp,
                                              float* __restrict__ yu16,
                                              float* __restrict__ aw_out) {
    int t = threadIdx.x, s = t >> 6, g = t & 63;
    const float4* X4 = (const float4*)x;
    float4 acc = make_float4(0.f, 0.f, 0.f, 0.f);
    for (int base = blockIdx.x * 8; base < N_NODES; base += GRID_POOL * 8) {
        float a0 = awu[base + s];
        float a1 = awu[base + 4 + s];
        float4 x0 = X4[(size_t)(base + s) * 64 + g];
        float4 x1 = X4[(size_t)(base + 4 + s) * 64 + g];
        acc.x = fmaf(a0, x0.x, acc.x); acc.y = fmaf(a0, x0.y, acc.y);
        acc.z = fmaf(a0, x0.z, acc.z); acc.w = fmaf(a0, x0.w, acc.w);
        acc.x = fmaf(a1, x1.x, acc.x); acc.y = fmaf(a1, x1.y, acc.y);
        acc.z = fmaf(a1, x1.z, acc.z); acc.w = fmaf(a1, x1.w, acc.w);
    }
    __shared__ float4 tmp4[4][64];
    tmp4[s][g] = acc;
    __syncthreads();
    const float* tmp = (const float*)tmp4;
    int c = t;
    float sum = tmp[0 * 256 + c] + tmp[1 * 256 + c] + tmp[2 * 256 + c] + tmp[3 * 256 + c];
    atomicAdd(&yu16[(blockIdx.x & (YCOPY - 1)) * 256 + c], sum);
    float inv = 1.0f / totalp[0];
    for (int i = blockIdx.x * 256 + t; i < N_NODES; i += GRID_POOL * 256)
        aw_out[i] = awu[i] * inv;
}

__global__ __launch_bounds__(256) void k_final(const float* __restrict__ yu16,
                                               const float* __restrict__ totalp,
                                               const float* __restrict__ Wv,
                                               const float* __restrict__ bv,
                                               float* __restrict__ out) {
    int t = threadIdx.x, b = blockIdx.x;
    float inv = 1.0f / totalp[0];
    float y = 0.0f;
    #pragma unroll
    for (int j = 0; j < YCOPY; ++j) y += yu16[j * 256 + t];
    y *= inv;
    float val = y * Wv[(size_t)t * CH + b];
    #pragma unroll
    for (int off = 32; off; off >>= 1) val += __shfl_down(val, off);
    __shared__ float sm[4];
    if ((t & 63) == 0) sm[t >> 6] = val;
    __syncthreads();
    if (t == 0) out[b] = sm[0] + sm[1] + sm[2] + sm[3] + bv[b];
}

extern "C" void kernel_launch(void* const* d_in, const int* in_sizes, int n_in,
                              void* d_out, int out_size, void* d_ws, size_t ws_size,
                              hipStream_t stream) {
    const float* x  = (const float*)d_in[0];
    const int*   ei = (const int*)d_in[1];
    const float* Wq = (const float*)d_in[2];
    const float* bq = (const float*)d_in[3];
    const float* Wk = (const float*)d_in[4];
    const float* bk = (const float*)d_in[5];
    const float* Wv = (const float*)d_in[6];
    const float* bv = (const float*)d_in[7];
    float* out = (float*)d_out;
    float* ws  = (float*)d_ws;

    if (ws_size >= (size_t)FULL_FLOATS * 4) {
        float*  mp     = ws + F_M;
        float*  totalp = ws + F_TOTAL;
        float4* qkmm   = (float4*)(ws + F_QKMM);
        float*  ptot   = ws + F_PTOT;
        int*    bstart = (int*)(ws + F_BSTART);
        int*    btot   = (int*)(ws + F_BTOT);
        float*  yu16   = ws + F_YU16;
        float*  awu    = ws + F_AWU;
        float*  q      = ws + F_Q;
        float*  k      = ws + F_K;
        int*    hist   = (int*)(ws + F_HIST);
        int2*   pairs  = (int2*)(ws + F_PAIRS);

        hipLaunchKernelGGL(k_init, dim3(16), dim3(256), 0, stream, yu16, 4096);
        hipLaunchKernelGGL(k_qk, dim3(GRID_QK), dim3(256), 0, stream,
                           x, Wq, bq, Wk, bk, q, k, qkmm);
        hipLaunchKernelGGL(k_hist, dim3(GA), dim3(256), 0, stream, ei, hist);
        hipLaunchKernelGGL(k_scan, dim3(NB), dim3(256), 0, stream, hist, btot);
        hipLaunchKernelGGL(k_bstart, dim3(1), dim3(256), 0, stream, btot, bstart, qkmm, mp);
        hipLaunchKernelGGL(k_scatter, dim3(GA), dim3(256), 0, stream,
                           ei, q, k, mp, hist, bstart, pairs);
        hipLaunchKernelGGL(k_agg, dim3(NB), dim3(256), 0, stream, pairs, bstart, awu, ptot);
        hipLaunchKernelGGL(k_total2, dim3(1), dim3(256), 0, stream, ptot, NB, totalp);
        hipLaunchKernelGGL(k_pool, dim3(GRID_POOL), dim3(256), 0, stream,
                           x, awu, totalp, yu16, out + CH);
        hipLaunchKernelGGL(k_final, dim3(CH), dim3(256), 0, stream,
                           yu16, totalp, Wv, bv, out);
    } else {
        float*  mp     = ws + B_M;
        float*  totalp = ws + B_TOTAL;
        float4* qkmm   = (float4*)(ws + B_QKMM);
        float*  ptot   = ws + B_PTOT;
        float*  yu16   = ws + B_YU16;
        float*  awu8   = ws + B_AWU8;
        float*  awu    = ws + B_AWU;
        float*  q      = ws + B_Q;
        float*  k      = ws + B_K;

        hipLaunchKernelGGL(k_init, dim3((FB_ZERO_CNT + 255) / 256), dim3(256), 0, stream,
                           ws + B_YU16, FB_ZERO_CNT);
        hipLaunchKernelGGL(k_qk, dim3(GRID_QK), dim3(256), 0, stream,
                           x, Wq, bq, Wk, bk, q, k, qkmm);
        hipLaunchKernelGGL(fb_bound, dim3(1), dim3(256), 0, stream, qkmm, mp);
        hipLaunchKernelGGL(fb_exp, dim3((N_EDGES + 255) / 256), dim3(256), 0, stream,
                           ei, q, k, mp, awu8);
        hipLaunchKernelGGL(fb_fold, dim3(NB), dim3(256), 0, stream, awu8, awu, ptot);
        hipLaunchKernelGGL(k_total2, dim3(1), dim3(256), 0, stream, ptot, NB, totalp);
        hipLaunchKernelGGL(k_pool, dim3(GRID_POOL), dim3(256), 0, stream,
                           x, awu, totalp, yu16, out + CH);
        hipLaunchKernelGGL(k_final, dim3(CH), dim3(256), 0, stream,
                           yu16, totalp, Wv, bv, out);
    }
}

// Round 4
// 296.958 us; speedup vs baseline: 2.1226x; 1.1385x over previous
//
#include <hip/hip_runtime.h>

#define N_NODES 100000
#define N_EDGES 3200000
#define CH 256

#define EPB_S 4096       // edges per sort block
#define GS 782           // ceil(N_EDGES/EPB_S); last block has 1024 edges
#define NB2 25           // buckets: bucket = row >> 12
#define BSZ 4096         // node span per bucket
#define G_AGG 10         // slices per bucket in aggregation
#define SLICE 79         // ceil(GS/G_AGG)
#define GRID_QK 1563     // 64 nodes/block
#define GRID_POOL 512
#define YCOPY 16

// ---- ws layout (float offsets) ----
#define OFF_M      0
#define OFF_TOTAL  1
#define OFF_QKMM   16                         // 1563 float4 = 6252
#define OFF_PTOT   6272                       // 400
#define OFF_YU16   6672                       // 4096 (zeroed by k_init)
#define OFF_PRE    10768                      // 782*26 ints = 20332
#define OFF_Q      31104                      // 100000
#define OFF_K      131104                     // 100000
#define OFF_AWU    231104                     // 100000
#define OFF_PART   331104                     // 25*10*4096 = 1024000
#define OFF_EX     1355104                    // 782*4096 = 3203072 floats
#define OFF_ROW    4558176                    // 3203072 u16 = 1601536 floats
// total 6159712 floats = 23.5 MiB (R3 confirmed ws >= 28 MB)

__global__ __launch_bounds__(256) void k_init(float* p, int cnt) {
    int i = blockIdx.x * 256 + threadIdx.x;
    if (i < cnt) p[i] = 0.0f;
}

// 64 nodes/block: q[n]=x.Wq+bq, k[n]=x.Wk+bk; per-block qk min/max partial
__global__ __launch_bounds__(256) void k_qk(const float* __restrict__ x,
                                            const float* __restrict__ Wq,
                                            const float* __restrict__ bq,
                                            const float* __restrict__ Wk,
                                            const float* __restrict__ bk,
                                            float* __restrict__ q,
                                            float* __restrict__ k,
                                            float4* __restrict__ qkmm) {
    int w = threadIdx.x >> 6, lane = threadIdx.x & 63;
    float4 wq = ((const float4*)Wq)[lane];
    float4 wk = ((const float4*)Wk)[lane];
    float bqs = bq[0], bks = bk[0];
    float qmax = -3.0e38f, qmin = 3.0e38f, kmax = -3.0e38f, kmin = 3.0e38f;
    int base = blockIdx.x * 64 + w * 16;
    #pragma unroll 4
    for (int i = 0; i < 16; ++i) {
        int n = base + i;
        if (n < N_NODES) {
            float4 xv = ((const float4*)(x + (size_t)n * CH))[lane];
            float dq = fmaf(xv.x, wq.x, fmaf(xv.y, wq.y, fmaf(xv.z, wq.z, xv.w * wq.w)));
            float dk = fmaf(xv.x, wk.x, fmaf(xv.y, wk.y, fmaf(xv.z, wk.z, xv.w * wk.w)));
            #pragma unroll
            for (int off = 32; off; off >>= 1) {
                dq += __shfl_down(dq, off);
                dk += __shfl_down(dk, off);
            }
            if (lane == 0) {
                float qq = dq + bqs, kk = dk + bks;
                q[n] = qq; k[n] = kk;
                qmax = fmaxf(qmax, qq); qmin = fminf(qmin, qq);
                kmax = fmaxf(kmax, kk); kmin = fminf(kmin, kk);
            }
        }
    }
    __shared__ float4 sm[4];
    if (lane == 0) sm[w] = make_float4(qmax, qmin, kmax, kmin);
    __syncthreads();
    if (threadIdx.x == 0) {
        float4 r = sm[0];
        #pragma unroll
        for (int j = 1; j < 4; ++j) {
            r.x = fmaxf(r.x, sm[j].x); r.y = fminf(r.y, sm[j].y);
            r.z = fmaxf(r.z, sm[j].z); r.w = fminf(r.w, sm[j].w);
        }
        qkmm[blockIdx.x] = r;
    }
}

// reduce qkmm -> m = lrelu(max corner product) >= max logit
__global__ __launch_bounds__(256) void k_bound(const float4* __restrict__ qkmm,
                                               float* __restrict__ mp) {
    int t = threadIdx.x;
    float qmax = -3.0e38f, qmin = 3.0e38f, kmax = -3.0e38f, kmin = 3.0e38f;
    for (int i = t; i < GRID_QK; i += 256) {
        float4 r = qkmm[i];
        qmax = fmaxf(qmax, r.x); qmin = fminf(qmin, r.y);
        kmax = fmaxf(kmax, r.z); kmin = fminf(kmin, r.w);
    }
    #pragma unroll
    for (int off = 32; off; off >>= 1) {
        qmax = fmaxf(qmax, __shfl_down(qmax, off));
        qmin = fminf(qmin, __shfl_down(qmin, off));
        kmax = fmaxf(kmax, __shfl_down(kmax, off));
        kmin = fminf(kmin, __shfl_down(kmin, off));
    }
    __shared__ float4 smf[4];
    if ((t & 63) == 0) smf[t >> 6] = make_float4(qmax, qmin, kmax, kmin);
    __syncthreads();
    if (t == 0) {
        float4 r = smf[0];
        #pragma unroll
        for (int j = 1; j < 4; ++j) {
            r.x = fmaxf(r.x, smf[j].x); r.y = fminf(r.y, smf[j].y);
            r.z = fmaxf(r.z, smf[j].z); r.w = fminf(r.w, smf[j].w);
        }
        float p = fmaxf(fmaxf(r.x * r.z, r.x * r.w), fmaxf(r.y * r.z, r.y * r.w));
        mp[0] = (p >= 0.0f) ? p : 0.2f * p;
    }
}

// Per-block LDS counting sort by bucket; coalesced write to block-private region.
__global__ __launch_bounds__(256) void k_sort(const int* __restrict__ ei,
                                              const float* __restrict__ q,
                                              const float* __restrict__ k,
                                              const float* __restrict__ mp,
                                              float* __restrict__ ex_out,
                                              unsigned short* __restrict__ row_out,
                                              int* __restrict__ pre) {
    __shared__ int cnt[NB2];
    __shared__ int pos[NB2];
    __shared__ int pref[NB2 + 1];
    __shared__ float lex[EPB_S];
    __shared__ unsigned short lrow[EPB_S];
    int t = threadIdx.x, blk = blockIdx.x;
    int e0 = blk * EPB_S;
    int ecnt = min(EPB_S, N_EDGES - e0);
    for (int i = t; i < NB2; i += 256) cnt[i] = 0;
    float m = mp[0];
    __syncthreads();

    int rr[16]; float ee[16];
    #pragma unroll
    for (int j = 0; j < 16; ++j) {
        int i = j * 256 + t;
        if (i < ecnt) {
            int r = ei[e0 + i], c = ei[N_EDGES + e0 + i];
            float v = q[r] * k[c];
            v = (v >= 0.0f) ? v : 0.2f * v;
            rr[j] = r;
            ee[j] = __expf(v - m);
            atomicAdd(&cnt[r >> 12], 1);
        }
    }
    __syncthreads();
    if (t == 0) {
        int run = 0;
        #pragma unroll
        for (int b = 0; b < NB2; ++b) { pref[b] = run; pos[b] = run; run += cnt[b]; }
        pref[NB2] = run;
    }
    __syncthreads();
    if (t < NB2 + 1) pre[blk * 26 + t] = pref[t];
    #pragma unroll
    for (int j = 0; j < 16; ++j) {
        int i = j * 256 + t;
        if (i < ecnt) {
            int b = rr[j] >> 12;
            int p = atomicAdd(&pos[b], 1);
            lex[p] = ee[j];
            lrow[p] = (unsigned short)(rr[j] & (BSZ - 1));
        }
    }
    __syncthreads();
    size_t base = (size_t)blk * EPB_S;
    for (int i = t; i < ecnt; i += 256) ex_out[base + i] = lex[i];
    unsigned* ro = (unsigned*)(row_out + base);
    const unsigned* lr = (const unsigned*)lrow;
    int words = (ecnt + 1) >> 1;
    for (int i = t; i < words; i += 256) ro[i] = lr[i];
}

// (bucket b, slice g): sum segment runs into LDS acc[4096], write dense partial
__global__ __launch_bounds__(256) void k_agg(const float* __restrict__ ex,
                                             const unsigned short* __restrict__ row,
                                             const int* __restrict__ pre,
                                             float* __restrict__ partial) {
    int b = blockIdx.x / G_AGG, g = blockIdx.x % G_AGG;
    __shared__ float acc[BSZ];
    __shared__ int seg[SLICE][2];
    int t = threadIdx.x;
    for (int i = t; i < BSZ; i += 256) acc[i] = 0.0f;
    int blk0 = g * SLICE, blk1 = min(blk0 + SLICE, GS);
    int nseg = blk1 - blk0;
    for (int i = t; i < nseg; i += 256) {
        seg[i][0] = pre[(blk0 + i) * 26 + b];
        seg[i][1] = pre[(blk0 + i) * 26 + b + 1];
    }
    __syncthreads();
    for (int sI = 0; sI < nseg; ++sI) {
        size_t base = (size_t)(blk0 + sI) * EPB_S;
        int s0 = seg[sI][0], s1 = seg[sI][1];
        for (int i = s0 + t; i < s1; i += 256)
            atomicAdd(&acc[row[base + i]], ex[base + i]);
    }
    __syncthreads();
    float* dst = partial + ((size_t)b * G_AGG + g) * BSZ;
    for (int i = t; i < BSZ; i += 256) dst[i] = acc[i];
}

// awu[n] = sum_g partial[b][g][n&4095]; per-block total partial
__global__ __launch_bounds__(256) void k_fold(const float* __restrict__ partial,
                                              float* __restrict__ awu,
                                              float* __restrict__ ptot) {
    int t = threadIdx.x;
    int n = blockIdx.x * 256 + t;
    float s = 0.0f;
    if (n < N_NODES) {
        int b = n >> 12, off = n & (BSZ - 1);
        const float* p = partial + (size_t)b * G_AGG * BSZ + off;
        #pragma unroll
        for (int g = 0; g < G_AGG; ++g) s += p[(size_t)g * BSZ];
        awu[n] = s;
    }
    float r = s;
    #pragma unroll
    for (int off = 32; off; off >>= 1) r += __shfl_down(r, off);
    __shared__ float sm[4];
    if ((t & 63) == 0) sm[t >> 6] = r;
    __syncthreads();
    if (t == 0) ptot[blockIdx.x] = sm[0] + sm[1] + sm[2] + sm[3];
}

__global__ __launch_bounds__(256) void k_total2(const float* __restrict__ ptot,
                                                int n, float* __restrict__ totalp) {
    int t = threadIdx.x;
    float s = 0.0f;
    for (int i = t; i < n; i += 256) s += ptot[i];
    #pragma unroll
    for (int off = 32; off; off >>= 1) s += __shfl_down(s, off);
    __shared__ float sm[4];
    if ((t & 63) == 0) sm[t >> 6] = s;
    __syncthreads();
    if (t == 0) totalp[0] = sm[0] + sm[1] + sm[2] + sm[3];
}

__global__ __launch_bounds__(256) void k_pool(const float* __restrict__ x,
                                              const float* __restrict__ awu,
                                              const float* __restrict__ totalp,
                                              float* __restrict__ yu16,
                                              float* __restrict__ aw_out) {
    int t = threadIdx.x, s = t >> 6, g = t & 63;
    const float4* X4 = (const float4*)x;
    float4 acc = make_float4(0.f, 0.f, 0.f, 0.f);
    for (int base = blockIdx.x * 8; base < N_NODES; base += GRID_POOL * 8) {
        float a0 = awu[base + s];
        float a1 = awu[base + 4 + s];
        float4 x0 = X4[(size_t)(base + s) * 64 + g];
        float4 x1 = X4[(size_t)(base + 4 + s) * 64 + g];
        acc.x = fmaf(a0, x0.x, acc.x); acc.y = fmaf(a0, x0.y, acc.y);
        acc.z = fmaf(a0, x0.z, acc.z); acc.w = fmaf(a0, x0.w, acc.w);
        acc.x = fmaf(a1, x1.x, acc.x); acc.y = fmaf(a1, x1.y, acc.y);
        acc.z = fmaf(a1, x1.z, acc.z); acc.w = fmaf(a1, x1.w, acc.w);
    }
    __shared__ float4 tmp4[4][64];
    tmp4[s][g] = acc;
    __syncthreads();
    const float* tmp = (const float*)tmp4;
    int c = t;
    float sum = tmp[0 * 256 + c] + tmp[1 * 256 + c] + tmp[2 * 256 + c] + tmp[3 * 256 + c];
    atomicAdd(&yu16[(blockIdx.x & (YCOPY - 1)) * 256 + c], sum);
    float inv = 1.0f / totalp[0];
    for (int i = blockIdx.x * 256 + t; i < N_NODES; i += GRID_POOL * 256)
        aw_out[i] = awu[i] * inv;
}

__global__ __launch_bounds__(256) void k_final(const float* __restrict__ yu16,
                                               const float* __restrict__ totalp,
                                               const float* __restrict__ Wv,
                                               const float* __restrict__ bv,
                                               float* __restrict__ out) {
    int t = threadIdx.x, b = blockIdx.x;
    float inv = 1.0f / totalp[0];
    float y = 0.0f;
    #pragma unroll
    for (int j = 0; j < YCOPY; ++j) y += yu16[j * 256 + t];
    y *= inv;
    float val = y * Wv[(size_t)t * CH + b];
    #pragma unroll
    for (int off = 32; off; off >>= 1) val += __shfl_down(val, off);
    __shared__ float sm[4];
    if ((t & 63) == 0) sm[t >> 6] = val;
    __syncthreads();
    if (t == 0) out[b] = sm[0] + sm[1] + sm[2] + sm[3] + bv[b];
}

extern "C" void kernel_launch(void* const* d_in, const int* in_sizes, int n_in,
                              void* d_out, int out_size, void* d_ws, size_t ws_size,
                              hipStream_t stream) {
    const float* x  = (const float*)d_in[0];
    const int*   ei = (const int*)d_in[1];
    const float* Wq = (const float*)d_in[2];
    const float* bq = (const float*)d_in[3];
    const float* Wk = (const float*)d_in[4];
    const float* bk = (const float*)d_in[5];
    const float* Wv = (const float*)d_in[6];
    const float* bv = (const float*)d_in[7];
    float* out = (float*)d_out;
    float* ws  = (float*)d_ws;

    float*          mp      = ws + OFF_M;
    float*          totalp  = ws + OFF_TOTAL;
    float4*         qkmm    = (float4*)(ws + OFF_QKMM);
    float*          ptot    = ws + OFF_PTOT;
    float*          yu16    = ws + OFF_YU16;
    int*            pre     = (int*)(ws + OFF_PRE);
    float*          q       = ws + OFF_Q;
    float*          k       = ws + OFF_K;
    float*          awu     = ws + OFF_AWU;
    float*          partial = ws + OFF_PART;
    float*          ex      = ws + OFF_EX;
    unsigned short* row     = (unsigned short*)(ws + OFF_ROW);

    hipLaunchKernelGGL(k_init, dim3(16), dim3(256), 0, stream, yu16, 4096);
    hipLaunchKernelGGL(k_qk, dim3(GRID_QK), dim3(256), 0, stream,
                       x, Wq, bq, Wk, bk, q, k, qkmm);
    hipLaunchKernelGGL(k_bound, dim3(1), dim3(256), 0, stream, qkmm, mp);
    hipLaunchKernelGGL(k_sort, dim3(GS), dim3(256), 0, stream,
                       ei, q, k, mp, ex, row, pre);
    hipLaunchKernelGGL(k_agg, dim3(NB2 * G_AGG), dim3(256), 0, stream,
                       ex, row, pre, partial);
    hipLaunchKernelGGL(k_fold, dim3((N_NODES + 255) / 256), dim3(256), 0, stream,
                       partial, awu, ptot);
    hipLaunchKernelGGL(k_total2, dim3(1), dim3(256), 0, stream,
                       ptot, (N_NODES + 255) / 256, totalp);
    hipLaunchKernelGGL(k_pool, dim3(GRID_POOL), dim3(256), 0, stream,
                       x, awu, totalp, yu16, out + CH);
    hipLaunchKernelGGL(k_final, dim3(CH), dim3(256), 0, stream,
                       yu16, totalp, Wv, bv, out);
}

// Round 5
// 269.633 us; speedup vs baseline: 2.3377x; 1.1013x over previous
//
#include <hip/hip_runtime.h>

#define N_NODES 100000
#define N_EDGES 3200000
#define CH 256

#define EPB_S 8192       // edges per sort block
#define GS 391           // ceil(N_EDGES/EPB_S); last block has 5120 edges
#define NB2 25           // buckets: bucket = row >> 12
#define BSZ 4096         // node span per bucket
#define G_AGG 10         // slices per bucket in aggregation
#define SLICE 40         // ceil(GS/G_AGG)
#define GRID_QK 1563     // 64 nodes/block
#define GRID_POOL 512
#define YCOPY 16

// ---- ws layout (float offsets) ----
#define OFF_TOTAL  0
#define OFF_PTOT   16        // 512
#define OFF_YU16   528       // 4096 (zeroed by k_qk blocks 0..15)
#define OFF_PRE    4624      // 391*26 = 10166 ints (pad to 10176)
#define OFF_Q      14800     // 100000
#define OFF_K      114800    // 100000
#define OFF_AWU    214800    // 100000
#define OFF_PART   314800    // 25*10*4096 = 1024000
#define OFF_EX     1338800   // 391*8192 = 3203072
#define OFF_ROW    4541872   // 3203072 u16 = 1601536 floats
// end = 6143408 floats ≈ 24.6 MiB (ws known >= 28 MiB from R3)

// q[n]=x[n,:].Wq+bq, k[n]=x[n,:].Wk+bk. 16-lane dot groups, 4 shuffle levels.
__global__ __launch_bounds__(256) void k_qk(const float* __restrict__ x,
                                            const float* __restrict__ Wq,
                                            const float* __restrict__ bq,
                                            const float* __restrict__ Wk,
                                            const float* __restrict__ bk,
                                            float* __restrict__ q,
                                            float* __restrict__ k,
                                            float* __restrict__ yu16) {
    int t = threadIdx.x;
    if (blockIdx.x < 16) yu16[blockIdx.x * 256 + t] = 0.0f;  // zero for k_pool atomics
    int w = t >> 6, lane = t & 63;
    int g = lane >> 4, seg = lane & 15;
    float4 wq4[4], wk4[4];
    #pragma unroll
    for (int j = 0; j < 4; ++j) {
        wq4[j] = ((const float4*)Wq)[seg + 16 * j];
        wk4[j] = ((const float4*)Wk)[seg + 16 * j];
    }
    float bqs = bq[0], bks = bk[0];
    int base = blockIdx.x * 64 + w * 16 + g;
    #pragma unroll
    for (int i = 0; i < 4; ++i) {
        int n = base + i * 4;
        if (n < N_NODES) {
            const float4* xr = (const float4*)(x + (size_t)n * CH);
            float dq = 0.0f, dk = 0.0f;
            #pragma unroll
            for (int j = 0; j < 4; ++j) {
                float4 xv = xr[seg + 16 * j];
                dq = fmaf(xv.x, wq4[j].x, fmaf(xv.y, wq4[j].y,
                     fmaf(xv.z, wq4[j].z, fmaf(xv.w, wq4[j].w, dq))));
                dk = fmaf(xv.x, wk4[j].x, fmaf(xv.y, wk4[j].y,
                     fmaf(xv.z, wk4[j].z, fmaf(xv.w, wk4[j].w, dk))));
            }
            dq += __shfl_down(dq, 8); dq += __shfl_down(dq, 4);
            dq += __shfl_down(dq, 2); dq += __shfl_down(dq, 1);
            dk += __shfl_down(dk, 8); dk += __shfl_down(dk, 4);
            dk += __shfl_down(dk, 2); dk += __shfl_down(dk, 1);
            if (seg == 0) { q[n] = dq + bqs; k[n] = dk + bks; }
        }
    }
}

// Per-block LDS counting sort (8192 edges, 512 thr); per-wave counters; exp(v) no shift.
__global__ __launch_bounds__(512) void k_sort(const int* __restrict__ ei,
                                              const float* __restrict__ q,
                                              const float* __restrict__ k,
                                              float* __restrict__ ex_out,
                                              unsigned short* __restrict__ row_out,
                                              int* __restrict__ pre) {
    __shared__ int cnt[8][NB2];
    __shared__ int base8[8][NB2];
    __shared__ int pref[NB2 + 1];
    __shared__ int bsum[NB2];
    __shared__ float lex[EPB_S];
    __shared__ unsigned short lrow[EPB_S];
    int t = threadIdx.x, blk = blockIdx.x, w = t >> 6;
    int e0 = blk * EPB_S;
    int ecnt = min(EPB_S, N_EDGES - e0);
    for (int i = t; i < 8 * NB2; i += 512) ((int*)cnt)[i] = 0;
    __syncthreads();
    int rr[16]; float ee[16];
    #pragma unroll
    for (int j = 0; j < 16; ++j) {
        int i = j * 512 + t;
        if (i < ecnt) {
            int r = ei[e0 + i], c = ei[N_EDGES + e0 + i];
            float v = q[r] * k[c];
            v = (v >= 0.0f) ? v : 0.2f * v;
            rr[j] = r; ee[j] = __expf(v);
            atomicAdd(&cnt[w][r >> 12], 1);
        } else rr[j] = -1;
    }
    __syncthreads();
    if (t < NB2) {               // intra-bucket scan over 8 waves
        int s = 0;
        #pragma unroll
        for (int ww = 0; ww < 8; ++ww) { base8[ww][t] = s; s += cnt[ww][t]; }
        bsum[t] = s;
    }
    __syncthreads();
    if (t == 0) {                // bucket prefix (25 iters)
        int run = 0;
        #pragma unroll
        for (int b = 0; b < NB2; ++b) { pref[b] = run; run += bsum[b]; }
        pref[NB2] = run;
    }
    __syncthreads();
    if (t < 8 * NB2) {
        int ww = t / NB2, b = t - ww * NB2;
        base8[ww][b] += pref[b];
    }
    if (t < NB2 + 1) pre[blk * 26 + t] = pref[t];
    __syncthreads();
    #pragma unroll
    for (int j = 0; j < 16; ++j) {
        if (rr[j] >= 0) {
            int b = rr[j] >> 12;
            int p = atomicAdd(&base8[w][b], 1);   // rank + place in one atomic
            lex[p] = ee[j];
            lrow[p] = (unsigned short)(rr[j] & (BSZ - 1));
        }
    }
    __syncthreads();
    size_t gb = (size_t)blk * EPB_S;
    for (int i = t; i < ecnt; i += 512) ex_out[gb + i] = lex[i];
    unsigned* ro = (unsigned*)(row_out + gb);
    const unsigned* lr = (const unsigned*)lrow;
    int words = (ecnt + 1) >> 1;
    for (int i = t; i < words; i += 512) ro[i] = lr[i];
}

// (bucket b, slice g): per-WAVE segment runs into LDS acc[4096] -> dense partial.
__global__ __launch_bounds__(512) void k_agg(const float* __restrict__ ex,
                                             const unsigned short* __restrict__ row,
                                             const int* __restrict__ pre,
                                             float* __restrict__ partial) {
    int b = blockIdx.x / G_AGG, g = blockIdx.x % G_AGG;
    __shared__ float acc[BSZ];
    int t = threadIdx.x, w = t >> 6, lane = t & 63;
    for (int i = t; i < BSZ; i += 512) acc[i] = 0.0f;
    __syncthreads();
    int sb0 = g * SLICE, sb1 = min(sb0 + SLICE, GS);
    for (int sb = sb0 + w; sb < sb1; sb += 8) {
        size_t gbase = (size_t)sb * EPB_S;
        int s0 = pre[sb * 26 + b], s1 = pre[sb * 26 + b + 1];
        for (int i = s0 + lane; i < s1; i += 64)
            atomicAdd(&acc[row[gbase + i]], ex[gbase + i]);
    }
    __syncthreads();
    float* dst = partial + ((size_t)b * G_AGG + g) * BSZ;
    for (int i = t; i < BSZ; i += 512) dst[i] = acc[i];
}

// awu[n] = sum_g partial[b][g][n&4095]; ptot[blk] = block partial of total
__global__ __launch_bounds__(256) void k_fold(const float* __restrict__ partial,
                                              float* __restrict__ awu,
                                              float* __restrict__ ptot) {
    int t = threadIdx.x;
    int n = blockIdx.x * 256 + t;
    float s = 0.0f;
    if (n < N_NODES) {
        int b = n >> 12, off = n & (BSZ - 1);
        const float* p = partial + (size_t)b * G_AGG * BSZ + off;
        #pragma unroll
        for (int g = 0; g < G_AGG; ++g) s += p[(size_t)g * BSZ];
        awu[n] = s;
    }
    float r = s;
    #pragma unroll
    for (int off = 32; off; off >>= 1) r += __shfl_down(r, off);
    __shared__ float sm[4];
    if ((t & 63) == 0) sm[t >> 6] = r;
    __syncthreads();
    if (t == 0) ptot[blockIdx.x] = sm[0] + sm[1] + sm[2] + sm[3];
}

// total inline; yu16 atomic partials; aw_out = awu/total
__global__ __launch_bounds__(256) void k_pool(const float* __restrict__ x,
                                              const float* __restrict__ awu,
                                              const float* __restrict__ ptot,
                                              float* __restrict__ totalp,
                                              float* __restrict__ yu16,
                                              float* __restrict__ aw_out) {
    int t = threadIdx.x, s = t >> 6, g = t & 63;
    // reduce ptot[0..390] -> total (every block, cheap)
    float ts = ptot[t] + ((t + 256 < GS) ? ptot[t + 256] : 0.0f);
    #pragma unroll
    for (int off = 32; off; off >>= 1) ts += __shfl_down(ts, off);
    __shared__ float sm[4];
    __shared__ float tot;
    if (g == 0) sm[s] = ts;
    __syncthreads();
    if (t == 0) {
        tot = sm[0] + sm[1] + sm[2] + sm[3];
        if (blockIdx.x == 0) totalp[0] = tot;
    }
    __syncthreads();
    float inv = 1.0f / tot;

    const float4* X4 = (const float4*)x;
    float4 acc = make_float4(0.f, 0.f, 0.f, 0.f);
    for (int base = blockIdx.x * 8; base < N_NODES; base += GRID_POOL * 8) {
        float a0 = awu[base + s];
        float a1 = awu[base + 4 + s];
        float4 x0 = X4[(size_t)(base + s) * 64 + g];
        float4 x1 = X4[(size_t)(base + 4 + s) * 64 + g];
        acc.x = fmaf(a0, x0.x, acc.x); acc.y = fmaf(a0, x0.y, acc.y);
        acc.z = fmaf(a0, x0.z, acc.z); acc.w = fmaf(a0, x0.w, acc.w);
        acc.x = fmaf(a1, x1.x, acc.x); acc.y = fmaf(a1, x1.y, acc.y);
        acc.z = fmaf(a1, x1.z, acc.z); acc.w = fmaf(a1, x1.w, acc.w);
    }
    __shared__ float4 tmp4[4][64];
    tmp4[s][g] = acc;
    __syncthreads();
    const float* tmp = (const float*)tmp4;
    float sum = tmp[0 * 256 + t] + tmp[1 * 256 + t] + tmp[2 * 256 + t] + tmp[3 * 256 + t];
    atomicAdd(&yu16[(blockIdx.x & (YCOPY - 1)) * 256 + t], sum);
    for (int i = blockIdx.x * 256 + t; i < N_NODES; i += GRID_POOL * 256)
        aw_out[i] = awu[i] * inv;
}

// grid 8: block j -> out[j*32 .. j*32+32)
__global__ __launch_bounds__(256) void k_final(const float* __restrict__ yu16,
                                               const float* __restrict__ totalp,
                                               const float* __restrict__ Wv,
                                               const float* __restrict__ bv,
                                               float* __restrict__ out) {
    __shared__ float ysh[256];
    __shared__ float red[256];
    int t = threadIdx.x;
    float inv = 1.0f / totalp[0];
    float yv = 0.0f;
    #pragma unroll
    for (int j = 0; j < YCOPY; ++j) yv += yu16[j * 256 + t];
    ysh[t] = yv * inv;
    __syncthreads();
    int c = blockIdx.x * 32 + (t & 31), rg = t >> 5;
    float acc = 0.0f;
    #pragma unroll
    for (int j = 0; j < 32; ++j) {
        int kk = rg * 32 + j;
        acc = fmaf(ysh[kk], Wv[(size_t)kk * CH + c], acc);
    }
    red[t] = acc;
    __syncthreads();
    if (t < 32) {
        float sv = 0.0f;
        #pragma unroll
        for (int j = 0; j < 8; ++j) sv += red[j * 32 + t];
        out[blockIdx.x * 32 + t] = sv + bv[blockIdx.x * 32 + t];
    }
}

extern "C" void kernel_launch(void* const* d_in, const int* in_sizes, int n_in,
                              void* d_out, int out_size, void* d_ws, size_t ws_size,
                              hipStream_t stream) {
    const float* x  = (const float*)d_in[0];
    const int*   ei = (const int*)d_in[1];
    const float* Wq = (const float*)d_in[2];
    const float* bq = (const float*)d_in[3];
    const float* Wk = (const float*)d_in[4];
    const float* bk = (const float*)d_in[5];
    const float* Wv = (const float*)d_in[6];
    const float* bv = (const float*)d_in[7];
    float* out = (float*)d_out;
    float* ws  = (float*)d_ws;

    float*          totalp  = ws + OFF_TOTAL;
    float*          ptot    = ws + OFF_PTOT;
    float*          yu16    = ws + OFF_YU16;
    int*            pre     = (int*)(ws + OFF_PRE);
    float*          q       = ws + OFF_Q;
    float*          k       = ws + OFF_K;
    float*          awu     = ws + OFF_AWU;
    float*          partial = ws + OFF_PART;
    float*          ex      = ws + OFF_EX;
    unsigned short* row     = (unsigned short*)(ws + OFF_ROW);

    hipLaunchKernelGGL(k_qk, dim3(GRID_QK), dim3(256), 0, stream,
                       x, Wq, bq, Wk, bk, q, k, yu16);
    hipLaunchKernelGGL(k_sort, dim3(GS), dim3(512), 0, stream,
                       ei, q, k, ex, row, pre);
    hipLaunchKernelGGL(k_agg, dim3(NB2 * G_AGG), dim3(512), 0, stream,
                       ex, row, pre, partial);
    hipLaunchKernelGGL(k_fold, dim3((N_NODES + 255) / 256), dim3(256), 0, stream,
                       partial, awu, ptot);
    hipLaunchKernelGGL(k_pool, dim3(GRID_POOL), dim3(256), 0, stream,
                       x, awu, ptot, totalp, yu16, out + CH);
    hipLaunchKernelGGL(k_final, dim3(8), dim3(256), 0, stream,
                       yu16, totalp, Wv, bv, out);
}